// Round 1
// baseline (176.465 us; speedup 1.0000x reference)
//
#include <hip/hip_runtime.h>
#include <stdint.h>

typedef _Float16 f16;
typedef f16 f16x8 __attribute__((ext_vector_type(8)));
typedef float f32x4 __attribute__((ext_vector_type(4)));

#define NUM_NODES 20000
#define NUM_EDGES 65536
#define WIDTH 64
#define EDGE_FEAT 6
#define HIDDEN 128
#define BM 256            // edges per workgroup
#define NCHUNK 129        // 128 h-chunks + 1 bias chunk (h==1)
#define XPAD 72           // x-tile row stride in halfs

#define XH_HALFS (NUM_NODES * WIDTH)   // 1,280,000 halfs for x in f16
#define XCONV_BLKS 625                 // 625 * 2048 halfs = 1,280,000 exactly
#define W2G_HALFS (NCHUNK * 4096)      // 528,384 halfs
#define HT_HALFS ((size_t)NCHUNK * NUM_EDGES)  // 8,454,144 halfs (16.9 MB)
#define HBLKS (NUM_EDGES / 256)        // 256 h-precompute blocks

// ---------------------------------------------------------------------------
// Prep: (a) W2g: 129 chunks of [64n x 64k] f16, transposed + XOR-granule
//       swizzled (same granule permutation stays within each 128B row, so it
//       is equally valid for direct global loads).
//       (b) x fp32 -> f16.
//       (c) h_T[129][E] f16: h = relu(ea@W1+b1) transposed, bias row = 1.
// ---------------------------------------------------------------------------
__global__ __launch_bounds__(256) void prep_kernel(
    const float* __restrict__ x, const float* __restrict__ W2,
    const float* __restrict__ b2, const float* __restrict__ ea,
    const float* __restrict__ W1, const float* __restrict__ b1,
    f16* __restrict__ ws_h)
{
  f16* x_h = ws_h;
  f16* W2g = ws_h + XH_HALFS;
  f16* hT  = ws_h + XH_HALFS + W2G_HALFS;
  const int blk = blockIdx.x, tid = threadIdx.x;

  if (blk < NCHUNK) {
    __shared__ float row[4096];
    const int ki = blk;
    const float* srcrow;
    if (ki < HIDDEN) {
      const float4* src = (const float4*)(W2 + (size_t)ki * 4096);
      #pragma unroll
      for (int i = 0; i < 4; ++i) {
        float4 v = src[tid + 256 * i];
        *(float4*)&row[(tid + 256 * i) * 4] = v;
      }
      __syncthreads();
      srcrow = row;
    } else {
      srcrow = b2;  // bias chunk, read straight from global
    }
    const int obase = tid * 16;
    f16x8 outv0, outv1;
    #pragma unroll
    for (int u = 0; u < 8; ++u) {
      int o = obase + u;
      int n = o >> 6, pg = (o >> 3) & 7, j = o & 7;
      int k = (pg ^ (n & 7)) * 8 + j;
      outv0[u] = (f16)srcrow[k * 64 + n];
    }
    #pragma unroll
    for (int u = 0; u < 8; ++u) {
      int o = obase + 8 + u;
      int n = o >> 6, pg = (o >> 3) & 7, j = o & 7;
      int k = (pg ^ (n & 7)) * 8 + j;
      outv1[u] = (f16)srcrow[k * 64 + n];
    }
    *(f16x8*)&W2g[(size_t)ki * 4096 + obase] = outv0;
    *(f16x8*)&W2g[(size_t)ki * 4096 + obase + 8] = outv1;
  } else if (blk < NCHUNK + XCONV_BLKS) {
    // x fp32 -> f16
    int idx = (blk - NCHUNK) * 2048 + tid * 8;
    if (idx + 8 <= XH_HALFS) {
      float4 a = *(const float4*)(x + idx);
      float4 b = *(const float4*)(x + idx + 4);
      f16x8 hv;
      hv[0] = (f16)a.x; hv[1] = (f16)a.y; hv[2] = (f16)a.z; hv[3] = (f16)a.w;
      hv[4] = (f16)b.x; hv[5] = (f16)b.y; hv[6] = (f16)b.z; hv[7] = (f16)b.w;
      *(f16x8*)&x_h[idx] = hv;
    }
  } else {
    // h precompute: 256 edges per block, 1 thread per edge
    __shared__ float w1s[EDGE_FEAT * HIDDEN];
    __shared__ float b1s[HIDDEN];
    for (int i = tid; i < EDGE_FEAT * HIDDEN; i += 256) w1s[i] = W1[i];
    if (tid < HIDDEN) b1s[tid] = b1[tid];
    __syncthreads();
    const int e = (blk - NCHUNK - XCONV_BLKS) * 256 + tid;
    const float* p = ea + (size_t)e * EDGE_FEAT;
    float a[6];
    #pragma unroll
    for (int f = 0; f < 6; ++f) a[f] = p[f];
    #pragma unroll 4
    for (int k = 0; k < HIDDEN; ++k) {
      float s = b1s[k];
      #pragma unroll
      for (int f = 0; f < 6; ++f) s = fmaf(a[f], w1s[f * HIDDEN + k], s);
      hT[(size_t)k * NUM_EDGES + e] = (f16)fmaxf(s, 0.f);  // wave-coalesced 2B
    }
    hT[(size_t)HIDDEN * NUM_EDGES + e] = (f16)1.f;  // bias row
  }
}

// ---------------------------------------------------------------------------
// Main fused kernel, K-split x2: grid 512.
//   blockIdx & 255  -> edge chunk (256 edges)
//   blockIdx >> 8   -> k-half: ki in [0,65) or [65,129)
// Barrier-free K-loop: B fragments load DIRECTLY from global (W2g is 1MB,
// L2-resident; all 8 waves/CU share the same 8KB chunk through L1) with a
// one-iteration register prefetch. h comes from precomputed h_T (HT=1) or
// in-loop recompute (HT=0 fallback when ws too small).
// ---------------------------------------------------------------------------
template<int HT>
__global__ __launch_bounds__(256, 2) void nnconv_kernel(
    const float* __restrict__ ea, const float* __restrict__ W1,
    const float* __restrict__ b1, const int* __restrict__ senders,
    const int* __restrict__ receivers, const f16* __restrict__ ws_h,
    float* __restrict__ out)
{
  const f16* x_h = ws_h;
  const f16* W2g = ws_h + XH_HALFS;
  const f16* hT  = ws_h + XH_HALFS + W2G_HALFS;
  __shared__ __align__(16) f16 xt[BM][XPAD];     // 36 KB, only LDS use

  const int tid = threadIdx.x;
  const int lane = tid & 63, wid = tid >> 6;
  const int quad = lane >> 4, l15 = lane & 15;
  const int chunk = blockIdx.x & 255;
  const int khalf = blockIdx.x >> 8;
  const int k0 = khalf ? 65 : 0;
  const int kcount = khalf ? 64 : 65;
  const int e0 = chunk * BM;
  const int rowbase = wid * 64;

  // ---- gather sender x rows (f16) into LDS: 1 thread per row, 128B each
  {
    int s = senders[e0 + tid];
    const uint4* src = (const uint4*)(x_h + (size_t)s * WIDTH);
    uint4* dst = (uint4*)&xt[tid][0];
    #pragma unroll
    for (int i = 0; i < 8; ++i) dst[i] = src[i];
  }

  // ---- per-lane edge_attr rows (fallback h recompute only)
  float ear[4][6];
  if (!HT) {
    #pragma unroll
    for (int t = 0; t < 4; ++t) {
      const float* p = ea + (size_t)(e0 + rowbase + t * 16 + l15) * EDGE_FEAT;
      #pragma unroll
      for (int f = 0; f < 6; ++f) ear[t][f] = p[f];
    }
  }

  // ---- per-lane B-fragment offsets within a chunk (swizzled), ki-invariant
  int boff[2][4];
  #pragma unroll
  for (int kc = 0; kc < 2; ++kc)
    #pragma unroll
    for (int nt = 0; nt < 4; ++nt) {
      int n = nt * 16 + l15;
      int g = kc * 4 + quad;
      boff[kc][nt] = n * 64 + (g ^ (n & 7)) * 8;
    }

  const int hrow = e0 + rowbase + l15;  // lane's base row into h_T rows

  // ---- preload iteration k0 operands into registers
  f16x8 bc[2][4];
  f16 hc[4];
  {
    const f16* Bp = W2g + (size_t)k0 * 4096;
    #pragma unroll
    for (int kc = 0; kc < 2; ++kc)
      #pragma unroll
      for (int nt = 0; nt < 4; ++nt)
        bc[kc][nt] = *(const f16x8*)(Bp + boff[kc][nt]);
    if (HT) {
      const f16* hp = hT + (size_t)k0 * NUM_EDGES + hrow;
      #pragma unroll
      for (int t = 0; t < 4; ++t) hc[t] = hp[t * 16];
    }
  }

  __syncthreads();  // xt ready (the only barrier in the kernel)

  // ---- x fragments (A-layout: m = l15, k-octet = quad), held all loop
  f16x8 xf[4][2];
  #pragma unroll
  for (int t = 0; t < 4; ++t)
    #pragma unroll
    for (int kc = 0; kc < 2; ++kc)
      xf[t][kc] = *(const f16x8*)&xt[rowbase + t * 16 + l15][kc * 32 + quad * 8];

  f32x4 acc[4][4];
  #pragma unroll
  for (int t = 0; t < 4; ++t)
    #pragma unroll
    for (int nt = 0; nt < 4; ++nt)
      acc[t][nt] = (f32x4){0.f, 0.f, 0.f, 0.f};

  for (int kk = 0; kk < kcount; ++kk) {
    const int ki = k0 + kk;
    const int kin = (kk + 1 < kcount) ? ki + 1 : ki;  // clamp, branch-free

    // prefetch next iteration's B fragments + h values (registers, no LDS)
    f16x8 bn[2][4];
    f16 hn[4];
    {
      const f16* Bp = W2g + (size_t)kin * 4096;
      #pragma unroll
      for (int kc = 0; kc < 2; ++kc)
        #pragma unroll
        for (int nt = 0; nt < 4; ++nt)
          bn[kc][nt] = *(const f16x8*)(Bp + boff[kc][nt]);
      if (HT) {
        const f16* hp = hT + (size_t)kin * NUM_EDGES + hrow;
        #pragma unroll
        for (int t = 0; t < 4; ++t) hn[t] = hp[t * 16];
      }
    }

    // h values for this ki
    f16 hv[4];
    if (HT) {
      #pragma unroll
      for (int t = 0; t < 4; ++t) hv[t] = hc[t];
    } else {
      if (ki < HIDDEN) {
        float b1c = b1[ki];
        float w1c[6];
        #pragma unroll
        for (int f = 0; f < 6; ++f) w1c[f] = W1[f * HIDDEN + ki];
        #pragma unroll
        for (int t = 0; t < 4; ++t) {
          float s = b1c;
          #pragma unroll
          for (int f = 0; f < 6; ++f) s = fmaf(ear[t][f], w1c[f], s);
          hv[t] = (f16)fmaxf(s, 0.f);
        }
      } else {
        #pragma unroll
        for (int t = 0; t < 4; ++t) hv[t] = (f16)1.f;  // bias chunk
      }
    }

    #pragma unroll
    for (int t = 0; t < 4; ++t) {
      f16x8 sa0 = xf[t][0] * hv[t];   // v_pk_mul_f16 x4
      f16x8 sa1 = xf[t][1] * hv[t];
      #pragma unroll
      for (int nt = 0; nt < 4; ++nt) {
        acc[t][nt] = __builtin_amdgcn_mfma_f32_16x16x32_f16(sa0, bc[0][nt], acc[t][nt], 0, 0, 0);
        acc[t][nt] = __builtin_amdgcn_mfma_f32_16x16x32_f16(sa1, bc[1][nt], acc[t][nt], 0, 0, 0);
      }
    }

    // rotate prefetched operands into current
    #pragma unroll
    for (int kc = 0; kc < 2; ++kc)
      #pragma unroll
      for (int nt = 0; nt < 4; ++nt)
        bc[kc][nt] = bn[kc][nt];
    if (HT) {
      #pragma unroll
      for (int t = 0; t < 4; ++t) hc[t] = hn[t];
    }
  }

  // ---- epilogue: C-layout row = quad*4 + reg, col = l15; scatter-add
  #pragma unroll
  for (int t = 0; t < 4; ++t) {
    int ebase = e0 + rowbase + t * 16 + quad * 4;
    int rc[4];
    #pragma unroll
    for (int r = 0; r < 4; ++r) rc[r] = receivers[ebase + r];
    #pragma unroll
    for (int nt = 0; nt < 4; ++nt) {
      int v = nt * 16 + l15;
      #pragma unroll
      for (int r = 0; r < 4; ++r)
        atomicAdd(out + (size_t)rc[r] * WIDTH + v, acc[t][nt][r]);
    }
  }
}

extern "C" void kernel_launch(void* const* d_in, const int* in_sizes, int n_in,
                              void* d_out, int out_size, void* d_ws, size_t ws_size,
                              hipStream_t stream) {
  const float* x  = (const float*)d_in[0];
  const float* ea = (const float*)d_in[1];
  const float* W1 = (const float*)d_in[2];
  const float* b1 = (const float*)d_in[3];
  const float* W2 = (const float*)d_in[4];
  const float* b2 = (const float*)d_in[5];
  const int* snd  = (const int*)d_in[6];
  const int* rcv  = (const int*)d_in[7];
  float* out = (float*)d_out;
  f16* wsh = (f16*)d_ws;

  const size_t need = ((size_t)XH_HALFS + W2G_HALFS + HT_HALFS) * sizeof(f16);
  const int use_ht = (ws_size >= need) ? 1 : 0;

  hipMemsetAsync(d_out, 0, (size_t)out_size * sizeof(float), stream);
  const int prep_grid = NCHUNK + XCONV_BLKS + (use_ht ? HBLKS : 0);
  prep_kernel<<<prep_grid, 256, 0, stream>>>(x, W2, b2, ea, W1, b1, wsh);
  if (use_ht)
    nnconv_kernel<1><<<2 * (NUM_EDGES / BM), 256, 0, stream>>>(ea, W1, b1, snd, rcv, wsh, out);
  else
    nnconv_kernel<0><<<2 * (NUM_EDGES / BM), 256, 0, stream>>>(ea, W1, b1, snd, rcv, wsh, out);
}

// Round 2
// 169.280 us; speedup vs baseline: 1.0424x; 1.0424x over previous
//
#include <hip/hip_runtime.h>
#include <stdint.h>

typedef _Float16 f16;
typedef f16 f16x8 __attribute__((ext_vector_type(8)));
typedef float f32x4 __attribute__((ext_vector_type(4)));

#define NUM_NODES 20000
#define NUM_EDGES 65536
#define WIDTH 64
#define EDGE_FEAT 6
#define HIDDEN 128
#define BM 256            // edges per workgroup
#define NCHUNK 129        // 128 h-chunks + 1 bias chunk (h==1)
#define XPAD 72           // x-tile row stride in halfs

#define XH_HALFS (NUM_NODES * WIDTH)   // 1,280,000 halfs for x in f16
#define XCONV_BLKS 625                 // 625 * 2048 halfs = 1,280,000 exactly
#define W2G_HALFS (NCHUNK * 4096)      // 528,384 halfs
#define HT_HALFS ((size_t)NCHUNK * NUM_EDGES)  // 8,454,144 halfs (16.9 MB)
#define HBLKS (NUM_EDGES / 256)        // 256 h-precompute blocks
#define OUT_FLOATS (NUM_NODES * WIDTH) // 1,280,000
#define ZBLKS 313                      // 313 * 4096 >= OUT_FLOATS

// direct global->LDS DMA, 16B per lane. lds dest must be wave-uniform base;
// HW writes dst + lane*16. src is per-lane.
__device__ __forceinline__ void gload_lds16(const f16* g, f16* l) {
  __builtin_amdgcn_global_load_lds(
      (const __attribute__((address_space(1))) unsigned int*)g,
      (__attribute__((address_space(3))) unsigned int*)l, 16, 0, 0);
}

// ---------------------------------------------------------------------------
// Prep: (a) W2g: 129 chunks of [64n x 64k] f16, transposed + XOR-granule
//       swizzled; (b) x fp32 -> f16; (c) zero `out`;
//       (d) h_T[129][E] f16: relu(ea@W1+b1)^T, bias row = 1.
// ---------------------------------------------------------------------------
__global__ __launch_bounds__(256) void prep_kernel(
    const float* __restrict__ x, const float* __restrict__ W2,
    const float* __restrict__ b2, const float* __restrict__ ea,
    const float* __restrict__ W1, const float* __restrict__ b1,
    f16* __restrict__ ws_h, float* __restrict__ out, int use_ht)
{
  f16* x_h = ws_h;
  f16* W2g = ws_h + XH_HALFS;
  f16* hT  = ws_h + XH_HALFS + W2G_HALFS;
  const int blk = blockIdx.x, tid = threadIdx.x;

  if (blk < NCHUNK) {
    __shared__ float row[4096];
    const int ki = blk;
    const float* srcrow;
    if (ki < HIDDEN) {
      const float4* src = (const float4*)(W2 + (size_t)ki * 4096);
      #pragma unroll
      for (int i = 0; i < 4; ++i) {
        float4 v = src[tid + 256 * i];
        *(float4*)&row[(tid + 256 * i) * 4] = v;
      }
      __syncthreads();
      srcrow = row;
    } else {
      srcrow = b2;  // bias chunk, read straight from global
    }
    const int obase = tid * 16;
    f16x8 outv0, outv1;
    #pragma unroll
    for (int u = 0; u < 8; ++u) {
      int o = obase + u;
      int n = o >> 6, pg = (o >> 3) & 7, j = o & 7;
      int k = (pg ^ (n & 7)) * 8 + j;
      outv0[u] = (f16)srcrow[k * 64 + n];
    }
    #pragma unroll
    for (int u = 0; u < 8; ++u) {
      int o = obase + 8 + u;
      int n = o >> 6, pg = (o >> 3) & 7, j = o & 7;
      int k = (pg ^ (n & 7)) * 8 + j;
      outv1[u] = (f16)srcrow[k * 64 + n];
    }
    *(f16x8*)&W2g[(size_t)ki * 4096 + obase] = outv0;
    *(f16x8*)&W2g[(size_t)ki * 4096 + obase + 8] = outv1;
  } else if (blk < NCHUNK + XCONV_BLKS) {
    // x fp32 -> f16
    int idx = (blk - NCHUNK) * 2048 + tid * 8;
    if (idx + 8 <= XH_HALFS) {
      float4 a = *(const float4*)(x + idx);
      float4 b = *(const float4*)(x + idx + 4);
      f16x8 hv;
      hv[0] = (f16)a.x; hv[1] = (f16)a.y; hv[2] = (f16)a.z; hv[3] = (f16)a.w;
      hv[4] = (f16)b.x; hv[5] = (f16)b.y; hv[6] = (f16)b.z; hv[7] = (f16)b.w;
      *(f16x8*)&x_h[idx] = hv;
    }
  } else if (blk < NCHUNK + XCONV_BLKS + ZBLKS) {
    // zero the output (replaces hipMemsetAsync dispatch)
    int base = (blk - NCHUNK - XCONV_BLKS) * 4096 + tid * 16;
    float4 z = {0.f, 0.f, 0.f, 0.f};
    #pragma unroll
    for (int i = 0; i < 4; ++i) {
      int idx = base + i * 4;
      if (idx + 4 <= OUT_FLOATS) *(float4*)(out + idx) = z;
    }
  } else if (use_ht) {
    // h precompute: 256 edges per block, 1 thread per edge
    __shared__ float w1s[EDGE_FEAT * HIDDEN];
    __shared__ float b1s[HIDDEN];
    for (int i = tid; i < EDGE_FEAT * HIDDEN; i += 256) w1s[i] = W1[i];
    if (tid < HIDDEN) b1s[tid] = b1[tid];
    __syncthreads();
    const int e = (blk - NCHUNK - XCONV_BLKS - ZBLKS) * 256 + tid;
    const float* p = ea + (size_t)e * EDGE_FEAT;
    float a[6];
    #pragma unroll
    for (int f = 0; f < 6; ++f) a[f] = p[f];
    #pragma unroll 4
    for (int k = 0; k < HIDDEN; ++k) {
      float s = b1s[k];
      #pragma unroll
      for (int f = 0; f < 6; ++f) s = fmaf(a[f], w1s[f * HIDDEN + k], s);
      hT[(size_t)k * NUM_EDGES + e] = (f16)fmaxf(s, 0.f);  // wave-coalesced 2B
    }
    hT[(size_t)HIDDEN * NUM_EDGES + e] = (f16)1.f;  // bias row
  }
}

// ---------------------------------------------------------------------------
// Main fused kernel, K-split x2: grid 512.
//   blockIdx & 255  -> edge chunk (256 edges)
//   blockIdx >> 8   -> k-half: ki in [0,65) or [65,129)
// T3 minimum-2-phase pipeline: per iter,
//   STAGE(k+1) via global_load_lds -> ds_read bf(k) -> MFMA ->
//   s_waitcnt vmcnt(0) -> raw s_barrier.
// One barrier per iter; the vmcnt wait is hidden under ds_read+MFMA.
// ---------------------------------------------------------------------------
template<int HT>
__global__ __launch_bounds__(256, 2) void nnconv_kernel(
    const float* __restrict__ ea, const float* __restrict__ W1,
    const float* __restrict__ b1, const int* __restrict__ senders,
    const int* __restrict__ receivers, const f16* __restrict__ ws_h,
    float* __restrict__ out)
{
  const f16* x_h = ws_h;
  const f16* W2g = ws_h + XH_HALFS;
  const f16* hT  = ws_h + XH_HALFS + W2G_HALFS;
  __shared__ __align__(16) f16 xt[BM][XPAD];     // 36 KB
  __shared__ __align__(16) f16 Bb[2][4096];      // 16 KB

  const int tid = threadIdx.x;
  const int lane = tid & 63, wid = tid >> 6;
  const int quad = lane >> 4, l15 = lane & 15;
  const int chunk = blockIdx.x & 255;
  const int khalf = blockIdx.x >> 8;
  const int k0 = khalf ? 65 : 0;
  const int kcount = khalf ? 64 : 65;
  const int e0 = chunk * BM;
  const int rowbase = wid * 64;

  // ---- gather sender x rows (f16) into LDS: 1 thread per row, 128B each
  {
    int s = senders[e0 + tid];
    const uint4* src = (const uint4*)(x_h + (size_t)s * WIDTH);
    uint4* dst = (uint4*)&xt[tid][0];
    #pragma unroll
    for (int i = 0; i < 8; ++i) dst[i] = src[i];
  }

  // ---- per-lane edge_attr rows (fallback h recompute only)
  float ear[4][6];
  if (!HT) {
    #pragma unroll
    for (int t = 0; t < 4; ++t) {
      const float* p = ea + (size_t)(e0 + rowbase + t * 16 + l15) * EDGE_FEAT;
      #pragma unroll
      for (int f = 0; f < 6; ++f) ear[t][f] = p[f];
    }
  }

  // ---- per-lane B-fragment offsets within a chunk (swizzled), ki-invariant
  int boff[2][4];
  #pragma unroll
  for (int kc = 0; kc < 2; ++kc)
    #pragma unroll
    for (int nt = 0; nt < 4; ++nt) {
      int n = nt * 16 + l15;
      int g = kc * 4 + quad;
      boff[kc][nt] = n * 64 + (g ^ (n & 7)) * 8;
    }

  const int hrow = e0 + rowbase + l15;
  // per-lane DMA source offset within a chunk; wave-uniform LDS dest offset
  const int stg_src = wid * 512 + (lane << 3);
  const int stg_dst = wid * 512;

  // ---- prologue: STAGE(k0) -> Bb[0]; h(k0) -> regs
  gload_lds16(W2g + (size_t)k0 * 4096 + stg_src, &Bb[0][stg_dst]);
  gload_lds16(W2g + (size_t)k0 * 4096 + 2048 + stg_src, &Bb[0][stg_dst + 2048]);
  f16 hc[4];
  if (HT) {
    const f16* hp = hT + (size_t)k0 * NUM_EDGES + hrow;
    #pragma unroll
    for (int t = 0; t < 4; ++t) hc[t] = hp[t * 16];
  }

  __syncthreads();  // xt + Bb[0] + hc all ready (full drain, once)

  // ---- x fragments (A-layout: m = l15, k-octet = quad), held all loop
  f16x8 xf[4][2];
  #pragma unroll
  for (int t = 0; t < 4; ++t)
    #pragma unroll
    for (int kc = 0; kc < 2; ++kc)
      xf[t][kc] = *(const f16x8*)&xt[rowbase + t * 16 + l15][kc * 32 + quad * 8];

  f32x4 acc[4][4];
  #pragma unroll
  for (int t = 0; t < 4; ++t)
    #pragma unroll
    for (int nt = 0; nt < 4; ++nt)
      acc[t][nt] = (f32x4){0.f, 0.f, 0.f, 0.f};

  for (int kk = 0; kk < kcount; ++kk) {
    const int ki = k0 + kk;
    const int kin = (kk + 1 < kcount) ? ki + 1 : ki;  // clamp, branch-free
    f16* buf = &Bb[kk & 1][0];
    f16* nbuf = &Bb[(kk + 1) & 1][0];

    // ---- issue STAGE(k+1): 2 DMA instrs per wave (writes land by vmcnt(0))
    {
      const f16* src = W2g + (size_t)kin * 4096 + stg_src;
      gload_lds16(src, nbuf + stg_dst);
      gload_lds16(src + 2048, nbuf + stg_dst + 2048);
    }
    // ---- prefetch next h values into regs
    f16 hn[4];
    if (HT) {
      const f16* hp = hT + (size_t)kin * NUM_EDGES + hrow;
      #pragma unroll
      for (int t = 0; t < 4; ++t) hn[t] = hp[t * 16];
    }

    // ---- h values for this ki
    f16 hv[4];
    if (HT) {
      #pragma unroll
      for (int t = 0; t < 4; ++t) hv[t] = hc[t];
    } else {
      if (ki < HIDDEN) {
        float b1c = b1[ki];
        float w1c[6];
        #pragma unroll
        for (int f = 0; f < 6; ++f) w1c[f] = W1[f * HIDDEN + ki];
        #pragma unroll
        for (int t = 0; t < 4; ++t) {
          float s = b1c;
          #pragma unroll
          for (int f = 0; f < 6; ++f) s = fmaf(ear[t][f], w1c[f], s);
          hv[t] = (f16)fmaxf(s, 0.f);
        }
      } else {
        #pragma unroll
        for (int t = 0; t < 4; ++t) hv[t] = (f16)1.f;  // bias chunk
      }
    }

    // ---- B fragments from current buffer (compiler tracks lgkmcnt)
    f16x8 bf[2][4];
    #pragma unroll
    for (int kc = 0; kc < 2; ++kc)
      #pragma unroll
      for (int nt = 0; nt < 4; ++nt)
        bf[kc][nt] = *(const f16x8*)&buf[boff[kc][nt]];

    #pragma unroll
    for (int t = 0; t < 4; ++t) {
      f16x8 sa0 = xf[t][0] * hv[t];   // v_pk_mul_f16 x4
      f16x8 sa1 = xf[t][1] * hv[t];
      #pragma unroll
      for (int nt = 0; nt < 4; ++nt) {
        acc[t][nt] = __builtin_amdgcn_mfma_f32_16x16x32_f16(sa0, bf[0][nt], acc[t][nt], 0, 0, 0);
        acc[t][nt] = __builtin_amdgcn_mfma_f32_16x16x32_f16(sa1, bf[1][nt], acc[t][nt], 0, 0, 0);
      }
    }

    // ---- pipeline fence: STAGE(k+1) landed everywhere, then barrier.
    // NO full drain: the wait happens after ds_read+MFMA hid the latency.
    __builtin_amdgcn_sched_barrier(0);
    asm volatile("s_waitcnt vmcnt(0)" ::: "memory");
    asm volatile("s_barrier" ::: "memory");
    __builtin_amdgcn_sched_barrier(0);

    if (HT) {
      #pragma unroll
      for (int t = 0; t < 4; ++t) hc[t] = hn[t];
    }
  }

  // ---- epilogue: C-layout row = quad*4 + reg, col = l15; scatter-add
  #pragma unroll
  for (int t = 0; t < 4; ++t) {
    int ebase = e0 + rowbase + t * 16 + quad * 4;
    int rc[4];
    #pragma unroll
    for (int r = 0; r < 4; ++r) rc[r] = receivers[ebase + r];
    #pragma unroll
    for (int nt = 0; nt < 4; ++nt) {
      int v = nt * 16 + l15;
      #pragma unroll
      for (int r = 0; r < 4; ++r)
        atomicAdd(out + (size_t)rc[r] * WIDTH + v, acc[t][nt][r]);
    }
  }
}

extern "C" void kernel_launch(void* const* d_in, const int* in_sizes, int n_in,
                              void* d_out, int out_size, void* d_ws, size_t ws_size,
                              hipStream_t stream) {
  const float* x  = (const float*)d_in[0];
  const float* ea = (const float*)d_in[1];
  const float* W1 = (const float*)d_in[2];
  const float* b1 = (const float*)d_in[3];
  const float* W2 = (const float*)d_in[4];
  const float* b2 = (const float*)d_in[5];
  const int* snd  = (const int*)d_in[6];
  const int* rcv  = (const int*)d_in[7];
  float* out = (float*)d_out;
  f16* wsh = (f16*)d_ws;

  const size_t need = ((size_t)XH_HALFS + W2G_HALFS + HT_HALFS) * sizeof(f16);
  const int use_ht = (ws_size >= need) ? 1 : 0;

  const int prep_grid = NCHUNK + XCONV_BLKS + ZBLKS + (use_ht ? HBLKS : 0);
  prep_kernel<<<prep_grid, 256, 0, stream>>>(x, W2, b2, ea, W1, b1, wsh, out, use_ht);
  if (use_ht)
    nnconv_kernel<1><<<2 * (NUM_EDGES / BM), 256, 0, stream>>>(ea, W1, b1, snd, rcv, wsh, out);
  else
    nnconv_kernel<0><<<2 * (NUM_EDGES / BM), 256, 0, stream>>>(ea, W1, b1, snd, rcv, wsh, out);
}